// Round 6
// baseline (66.505 us; speedup 1.0000x reference)
//
#include <hip/hip_runtime.h>

#define B_ 8
#define C_ 4
#define H_ 256
#define W_ 256
#define NIMG 32
#define HW 65536
#define NROW 2048                 // B_ * H_
#define INF2 (1.0e6f * 1.0e6f)   // fl(1e12), same as reference capped scan squared

// One block per (b, h). Only the pixel's OWN class c = y[h][w] has a
// nontrivial EDT; the other 3 channels contribute p_c * 1. Per row emit 9
// partials: A_c = sum_{yv=c} p*d, M_c = max_{yv=c} d (c=0..3), T = sum (1-p_yv).
// The LAST block to finish (counter) also performs the final reduction.
__global__ __launch_bounds__(256) void fused_kernel(const int* __restrict__ y,
                                                    const float* __restrict__ x,
                                                    float* __restrict__ P,
                                                    unsigned* __restrict__ cnt,
                                                    float* __restrict__ out) {
    const int row = blockIdx.x;          // b*H + h
    const int b = row >> 8;
    const int h = row & (H_ - 1);
    const int tx = threadIdx.x;          // column
    const int* __restrict__ yb = y + b * HW;

    // ---- issue ALL independent loads upfront: 4 x-channels, own label,
    // ---- and the 8 neighbor rows (k=1..4) for the column-distance search.
    const float* __restrict__ xb = x + (size_t)b * (C_ * HW) + h * W_ + tx;
    const float x0 = xb[0];
    const float x1 = xb[HW];
    const float x2 = xb[2 * HW];
    const float x3 = xb[3 * HW];
    const int yv = yb[h * W_ + tx];
    int nbu[4], nbd[4];                  // clamped addresses; masked below
#pragma unroll
    for (int k = 1; k <= 4; ++k) {
        nbu[k - 1] = yb[max(h - k, 0) * W_ + tx];
        nbd[k - 1] = yb[min(h + k, H_ - 1) * W_ + tx];
    }

    // ---- column distance^2: nearest row with a different label ----
    float g2 = INF2;
    bool done = false;
#pragma unroll
    for (int k = 1; k <= 4; ++k) {
        const bool hit = ((h - k >= 0) && nbu[k - 1] != yv) ||
                         ((h + k < H_) && nbd[k - 1] != yv);
        if (!done && hit) { g2 = (float)(k * k); done = true; }
    }
    if (__any(!done)) {                  // rare: unresolved past k=4
        for (int k = 5; k < H_; ++k) {
            const int hu = h - k, hd = h + k;
            const int u = yb[max(hu, 0) * W_ + tx];
            const int dn = yb[min(hd, H_ - 1) * W_ + tx];
            const bool hit = ((hu >= 0) && u != yv) || ((hd < H_) && dn != yv);
            if (!done && hit) { g2 = (float)(k * k); done = true; }
            if (__all(done)) break;
            if (hu < 0 && hd >= H_) break;
        }
    }

    __shared__ uint2 s2[W_];             // {g2 bits, label}
    s2[tx] = make_uint2(__float_as_uint(g2), (unsigned)yv);
    __syncthreads();

    // ---- exact min-plus along W, adaptive radius, clamped indices ----
    // cand(j,k) = (label[j]==yv ? g2col[j] : 0) + k^2 ; a clamped j is
    // dominated by its true-k evaluation, so clamping never changes the min.
    const unsigned cu = (unsigned)yv;
    float m = g2;                        // j = x candidate
#define CAND(J, K2) ({ int j_ = (J); j_ = min(max(j_, 0), W_ - 1);            \
                       const uint2 v_ = s2[j_];                               \
                       (((v_.y == cu) ? __uint_as_float(v_.x) : 0.0f) + (K2)); })
    m = fminf(m, fminf(CAND(tx - 1, 1.0f),  CAND(tx + 1, 1.0f)));
    m = fminf(m, fminf(CAND(tx - 2, 4.0f),  CAND(tx + 2, 4.0f)));
    m = fminf(m, fminf(CAND(tx - 3, 9.0f),  CAND(tx + 3, 9.0f)));
    m = fminf(m, fminf(CAND(tx - 4, 16.0f), CAND(tx + 4, 16.0f)));
    if (__any(m > 25.0f)) {
        float k2 = 25.0f, tk1 = 11.0f;   // k^2, 2k+1 (exact ints in f32)
        for (int k = 5; k < W_; ++k) {
            m = fminf(m, fminf(CAND(tx - k, k2), CAND(tx + k, k2)));
            k2 += tk1; tk1 += 2.0f;
            if (__all(k2 >= m)) break;   // next k can't improve any lane
        }
    }
#undef CAND
    const float d = sqrtf(m);            // own-class distance (>= 1)

    // ---- softmax over channels; contribution split ----
    const float xm = fmaxf(fmaxf(x0, x1), fmaxf(x2, x3));
    const float e0 = __expf(x0 - xm), e1 = __expf(x1 - xm);
    const float e2 = __expf(x2 - xm), e3 = __expf(x3 - xm);
    const float se = e0 + e1 + e2 + e3;
    const float inv = 1.0f / se;
    const float ec = (yv == 0) ? e0 : (yv == 1) ? e1 : (yv == 2) ? e2 : e3;
    const float p = ec * inv;            // own-class probability
    float T = (se - ec) * inv;           // other 3 classes: r = 1
    const float a = p * d;               // own class: needs /(mx+eps) later

    float A0 = (yv == 0) ? a : 0.0f, M0 = (yv == 0) ? d : 0.0f;
    float A1 = (yv == 1) ? a : 0.0f, M1 = (yv == 1) ? d : 0.0f;
    float A2 = (yv == 2) ? a : 0.0f, M2 = (yv == 2) ? d : 0.0f;
    float A3 = (yv == 3) ? a : 0.0f, M3 = (yv == 3) ? d : 0.0f;

    // ---- fixed-order wave butterfly + cross-wave combine ----
#pragma unroll
    for (int off = 1; off < 64; off <<= 1) {
        A0 += __shfl_xor(A0, off); A1 += __shfl_xor(A1, off);
        A2 += __shfl_xor(A2, off); A3 += __shfl_xor(A3, off);
        T  += __shfl_xor(T,  off);
        M0 = fmaxf(M0, __shfl_xor(M0, off)); M1 = fmaxf(M1, __shfl_xor(M1, off));
        M2 = fmaxf(M2, __shfl_xor(M2, off)); M3 = fmaxf(M3, __shfl_xor(M3, off));
    }
    __shared__ float red[4][9];
    const int wid = tx >> 6;
    if ((tx & 63) == 0) {
        red[wid][0] = A0; red[wid][1] = A1; red[wid][2] = A2; red[wid][3] = A3;
        red[wid][4] = M0; red[wid][5] = M1; red[wid][6] = M2; red[wid][7] = M3;
        red[wid][8] = T;
    }
    __syncthreads();
    if (tx < 9) {   // slots 0-3: A sums, 4-7: M maxes, 8: T sum
        const float v0 = red[0][tx], v1 = red[1][tx], v2 = red[2][tx], v3 = red[3][tx];
        const float r = (tx >= 4 && tx < 8) ? fmaxf(fmaxf(v0, v1), fmaxf(v2, v3))
                                            : (v0 + v1) + (v2 + v3);
        P[tx * NROW + row] = r;
    }

    // ---- last-block finish (canonical threadFenceReduction pattern) ----
    __syncthreads();                     // block's P stores done & visible block-wide
    __shared__ unsigned lastflag;
    if (tx == 0) {
        __threadfence();                 // release this block's P stores (device scope)
        lastflag = (atomicAdd(cnt, 1u) == NROW - 1) ? 1u : 0u;
    }
    __syncthreads();
    if (lastflag) {
        __threadfence();                 // acquire: all other blocks' P stores visible
        const int t = tx;                // 256 threads; 32 groups of 8 = (b,c)
        const int g = t >> 3, l = t & 7;
        const int bb = g >> 2, cc = g & 3;
        const float* Pa = P + cc * NROW + bb * H_;
        const float* Pm = P + (4 + cc) * NROW + bb * H_;
        float aa = 0.0f, mm = 0.0f;
#pragma unroll 8
        for (int i = 0; i < 32; ++i) {
            aa += Pa[l + (i << 3)];
            mm = fmaxf(mm, Pm[l + (i << 3)]);
        }
#pragma unroll
        for (int off = 1; off < 8; off <<= 1) {
            aa += __shfl_xor(aa, off);
            mm = fmaxf(mm, __shfl_xor(mm, off));
        }
        float tt = 0.0f;
        const float* Pt = P + 8 * NROW;
#pragma unroll
        for (int i = 0; i < 8; ++i) tt += Pt[t + (i << 8)];
#pragma unroll
        for (int off = 1; off < 64; off <<= 1) tt += __shfl_xor(tt, off);
        __shared__ float sV[32];
        __shared__ float sT[4];
        if (l == 0) sV[g] = aa / (mm + 1e-15f);
        if ((t & 63) == 0) sT[t >> 6] = tt;
        __syncthreads();
        if (t == 0) {
            float S = 0.0f;
#pragma unroll
            for (int i = 0; i < 32; ++i) S += sV[i];
            const float TT = (sT[0] + sT[1]) + (sT[2] + sT[3]);
            out[0] = (TT - S) * (1.0f / 2097152.0f);   // / (B*C*H*W)
        }
    }
}

extern "C" void kernel_launch(void* const* d_in, const int* in_sizes, int n_in,
                              void* d_out, int out_size, void* d_ws, size_t ws_size,
                              hipStream_t stream) {
    const float* x = (const float*)d_in[0];   // [B, C, H, W] f32
    const int* y = (const int*)d_in[1];       // [B, 1, H, W] i32
    float* out = (float*)d_out;               // scalar f32
    float* P = (float*)d_ws;                  // [9][NROW] partials (72 KB)
    unsigned* cnt = (unsigned*)(P + 9 * NROW);

    hipMemsetAsync(cnt, 0, sizeof(unsigned), stream);  // graph-safe 4B reset
    fused_kernel<<<NROW, 256, 0, stream>>>(y, x, P, cnt, out);
}

// Round 7
// 55.784 us; speedup vs baseline: 1.1922x; 1.1922x over previous
//
#include <hip/hip_runtime.h>

#define B_ 8
#define C_ 4
#define H_ 256
#define W_ 256
#define NIMG 32
#define HW 65536
#define NROW 2048                 // B_ * H_
#define INF2 (1.0e6f * 1.0e6f)   // fl(1e12), same as reference capped scan squared
#define ASCALE 1048576.0          // 2^20 fixed-point for A sums
#define TSCALE 1073741824.0       // 2^30 fixed-point for T sum

// Workspace layout (zeroed by one 512B memset each launch):
//   [0..31]  accA  : i64 fixed-point sums of p*d per (b,c)
//   [32]     accT  : i64 fixed-point global sum of (1 - p_yv)
//   [33..40] accM  : 32 x u32 float-bits max d per (b,c)  (+ cnt in tail)
struct Acc {
    unsigned long long A[NIMG];
    unsigned long long T;
    unsigned M[NIMG];
    unsigned cnt;
};

// One block per (b, h). Only the pixel's OWN class c = y[h][w] has a
// nontrivial EDT; the other 3 channels contribute p_c * 1. Blocks accumulate
// into Acc via deterministic integer atomics; the last block (counter) reads
// the accumulators back with atomics (coherent, no fence) and writes out.
__global__ __launch_bounds__(256) void fused_kernel(const int* __restrict__ y,
                                                    const float* __restrict__ x,
                                                    Acc* __restrict__ acc,
                                                    float* __restrict__ out) {
    const int row = blockIdx.x;          // b*H + h
    const int b = row >> 8;
    const int h = row & (H_ - 1);
    const int tx = threadIdx.x;          // column
    const int* __restrict__ yb = y + b * HW;

    // ---- issue ALL independent loads upfront: 4 x-channels, own label,
    // ---- and the 8 neighbor rows (k=1..4) for the column-distance search.
    const float* __restrict__ xb = x + (size_t)b * (C_ * HW) + h * W_ + tx;
    const float x0 = xb[0];
    const float x1 = xb[HW];
    const float x2 = xb[2 * HW];
    const float x3 = xb[3 * HW];
    const int yv = yb[h * W_ + tx];
    int nbu[4], nbd[4];                  // clamped addresses; masked below
#pragma unroll
    for (int k = 1; k <= 4; ++k) {
        nbu[k - 1] = yb[max(h - k, 0) * W_ + tx];
        nbd[k - 1] = yb[min(h + k, H_ - 1) * W_ + tx];
    }

    // ---- column distance^2: nearest row with a different label ----
    float g2 = INF2;
    bool done = false;
#pragma unroll
    for (int k = 1; k <= 4; ++k) {
        const bool hit = ((h - k >= 0) && nbu[k - 1] != yv) ||
                         ((h + k < H_) && nbd[k - 1] != yv);
        if (!done && hit) { g2 = (float)(k * k); done = true; }
    }
    if (__any(!done)) {                  // rare: unresolved past k=4
        for (int k = 5; k < H_; ++k) {
            const int hu = h - k, hd = h + k;
            const int u = yb[max(hu, 0) * W_ + tx];
            const int dn = yb[min(hd, H_ - 1) * W_ + tx];
            const bool hit = ((hu >= 0) && u != yv) || ((hd < H_) && dn != yv);
            if (!done && hit) { g2 = (float)(k * k); done = true; }
            if (__all(done)) break;
            if (hu < 0 && hd >= H_) break;
        }
    }

    __shared__ uint2 s2[W_];             // {g2 bits, label}
    s2[tx] = make_uint2(__float_as_uint(g2), (unsigned)yv);
    __syncthreads();

    // ---- exact min-plus along W, adaptive radius, clamped indices ----
    // cand(j,k) = (label[j]==yv ? g2col[j] : 0) + k^2 ; a clamped j is
    // dominated by its true-k evaluation, so clamping never changes the min.
    const unsigned cu = (unsigned)yv;
    float m = g2;                        // j = x candidate
#define CAND(J, K2) ({ int j_ = (J); j_ = min(max(j_, 0), W_ - 1);            \
                       const uint2 v_ = s2[j_];                               \
                       (((v_.y == cu) ? __uint_as_float(v_.x) : 0.0f) + (K2)); })
    m = fminf(m, fminf(CAND(tx - 1, 1.0f),  CAND(tx + 1, 1.0f)));
    m = fminf(m, fminf(CAND(tx - 2, 4.0f),  CAND(tx + 2, 4.0f)));
    m = fminf(m, fminf(CAND(tx - 3, 9.0f),  CAND(tx + 3, 9.0f)));
    m = fminf(m, fminf(CAND(tx - 4, 16.0f), CAND(tx + 4, 16.0f)));
    if (__any(m > 25.0f)) {
        float k2 = 25.0f, tk1 = 11.0f;   // k^2, 2k+1 (exact ints in f32)
        for (int k = 5; k < W_; ++k) {
            m = fminf(m, fminf(CAND(tx - k, k2), CAND(tx + k, k2)));
            k2 += tk1; tk1 += 2.0f;
            if (__all(k2 >= m)) break;   // next k can't improve any lane
        }
    }
#undef CAND
    const float d = sqrtf(m);            // own-class distance (>= 1)

    // ---- softmax over channels; contribution split ----
    const float xm = fmaxf(fmaxf(x0, x1), fmaxf(x2, x3));
    const float e0 = __expf(x0 - xm), e1 = __expf(x1 - xm);
    const float e2 = __expf(x2 - xm), e3 = __expf(x3 - xm);
    const float se = e0 + e1 + e2 + e3;
    const float inv = 1.0f / se;
    const float ec = (yv == 0) ? e0 : (yv == 1) ? e1 : (yv == 2) ? e2 : e3;
    const float p = ec * inv;            // own-class probability
    float T = (se - ec) * inv;           // other 3 classes: r = 1
    const float a = p * d;               // own class: needs /(mx+eps) later

    float A0 = (yv == 0) ? a : 0.0f, M0 = (yv == 0) ? d : 0.0f;
    float A1 = (yv == 1) ? a : 0.0f, M1 = (yv == 1) ? d : 0.0f;
    float A2 = (yv == 2) ? a : 0.0f, M2 = (yv == 2) ? d : 0.0f;
    float A3 = (yv == 3) ? a : 0.0f, M3 = (yv == 3) ? d : 0.0f;

    // ---- fixed-order wave butterfly + cross-wave combine ----
#pragma unroll
    for (int off = 1; off < 64; off <<= 1) {
        A0 += __shfl_xor(A0, off); A1 += __shfl_xor(A1, off);
        A2 += __shfl_xor(A2, off); A3 += __shfl_xor(A3, off);
        T  += __shfl_xor(T,  off);
        M0 = fmaxf(M0, __shfl_xor(M0, off)); M1 = fmaxf(M1, __shfl_xor(M1, off));
        M2 = fmaxf(M2, __shfl_xor(M2, off)); M3 = fmaxf(M3, __shfl_xor(M3, off));
    }
    __shared__ float red[4][9];
    const int wid = tx >> 6;
    if ((tx & 63) == 0) {
        red[wid][0] = A0; red[wid][1] = A1; red[wid][2] = A2; red[wid][3] = A3;
        red[wid][4] = M0; red[wid][5] = M1; red[wid][6] = M2; red[wid][7] = M3;
        red[wid][8] = T;
    }
    __syncthreads();
    if (tx < 9) {   // slots 0-3: A sums, 4-7: M maxes, 8: T sum
        const float v0 = red[0][tx], v1 = red[1][tx], v2 = red[2][tx], v3 = red[3][tx];
        if (tx < 4) {                    // A_c: fixed-point i64 add (exact commute)
            const float v = (v0 + v1) + (v2 + v3);
            atomicAdd(&acc->A[b * C_ + tx],
                      (unsigned long long)(long long)((double)v * ASCALE + 0.5));
        } else if (tx < 8) {             // M_c: float-bits max (exact, d >= 0)
            const float v = fmaxf(fmaxf(v0, v1), fmaxf(v2, v3));
            atomicMax(&acc->M[b * C_ + (tx - 4)], __float_as_uint(v));
        } else {                         // T: fixed-point i64 add
            const float v = (v0 + v1) + (v2 + v3);
            atomicAdd(&acc->T,
                      (unsigned long long)(long long)((double)v * TSCALE + 0.5));
        }
    }

    // ---- last-block finish: atomic-only communication, NO threadfence ----
    // __syncthreads drains each thread's vmcnt (barrier drain), so this
    // block's data atomics are at the coherent point before cnt increments.
    __syncthreads();
    __shared__ unsigned lastflag;
    if (tx == 0)
        lastflag = (atomicAdd(&acc->cnt, 1u) == NROW - 1) ? 1u : 0u;
    __syncthreads();
    if (lastflag) {
        // coherent read-back via returning atomics; fixed-order combine
        float s = 0.0f;
        if (tx < NIMG) {
            const unsigned long long av = atomicAdd(&acc->A[tx], 0ULL);
            const unsigned mv = atomicMax(&acc->M[tx], 0u);
            const float Af = (float)((double)av * (1.0 / ASCALE));
            const float Mf = __uint_as_float(mv);
            s = Af / (Mf + 1e-15f);
        }
#pragma unroll
        for (int off = 1; off < 64; off <<= 1) s += __shfl_xor(s, off);
        __shared__ float sS;
        if (tx == 32) sS = s;            // lanes 32..63 held zeros + mirror sum
        __syncthreads();
        if (tx == 0) {
            const unsigned long long tv = atomicAdd(&acc->T, 0ULL);
            const float Tf = (float)((double)tv * (1.0 / TSCALE));
            out[0] = (Tf - sS) * (1.0f / 2097152.0f);   // / (B*C*H*W)
        }
    }
}

extern "C" void kernel_launch(void* const* d_in, const int* in_sizes, int n_in,
                              void* d_out, int out_size, void* d_ws, size_t ws_size,
                              hipStream_t stream) {
    const float* x = (const float*)d_in[0];   // [B, C, H, W] f32
    const int* y = (const int*)d_in[1];       // [B, 1, H, W] i32
    float* out = (float*)d_out;               // scalar f32
    Acc* acc = (Acc*)d_ws;

    hipMemsetAsync(acc, 0, sizeof(Acc), stream);   // 404 B, graph-safe
    fused_kernel<<<NROW, 256, 0, stream>>>(y, x, acc, out);
}

// Round 8
// 15.125 us; speedup vs baseline: 4.3970x; 3.6882x over previous
//
#include <hip/hip_runtime.h>

#define B_ 8
#define C_ 4
#define H_ 256
#define W_ 256
#define NIMG 32
#define HW 65536
#define RPB 4                     // rows per block
#define NBLK (B_ * H_ / RPB)      // 512 blocks
#define INF2 (1.0e6f * 1.0e6f)   // fl(1e12), same as reference capped scan squared

// One block per (b, 4 consecutive rows). Only the pixel's OWN class c=y[h][w]
// has a nontrivial EDT; other 3 channels contribute p_c*1. Adjacent rows share
// the k<=4 neighbor window: 12 y-rows serve all 4 rows. Per block emit 9
// partials: A_c = sum p*d, M_c = max d (c=0..3), T = sum (1-p_yv).
__global__ __launch_bounds__(256) void fused_kernel(const int* __restrict__ y,
                                                    const float* __restrict__ x,
                                                    float* __restrict__ P) {
    const int blk = blockIdx.x;          // b*64 + rb
    const int b = blk >> 6;
    const int h0 = (blk & 63) * RPB;     // first of 4 rows
    const int tx = threadIdx.x;          // column
    const int* __restrict__ yb = y + b * HW;

    // ---- all independent loads upfront: 12 y-rows (h0-4..h0+7, clamped)
    // ---- and 16 x values (4 rows x 4 channels).
    int yr[12];
#pragma unroll
    for (int i = 0; i < 12; ++i) {
        const int hh = min(max(h0 - 4 + i, 0), H_ - 1);
        yr[i] = yb[hh * W_ + tx];
    }
    float xv[RPB][C_];
    const float* __restrict__ xb = x + (size_t)b * (C_ * HW) + h0 * W_ + tx;
#pragma unroll
    for (int r = 0; r < RPB; ++r)
#pragma unroll
        for (int c = 0; c < C_; ++c) xv[r][c] = xb[c * HW + r * W_];

    // ---- column distance^2 per row: nearest row with a different label ----
    float g2v[RPB];
#pragma unroll
    for (int r = 0; r < RPB; ++r) {
        const int yv = yr[4 + r];
        const int h = h0 + r;
        float g2 = INF2;
        bool done = false;
#pragma unroll
        for (int k = 1; k <= 4; ++k) {
            const bool hit = ((h - k >= 0) && yr[4 + r - k] != yv) ||
                             ((h + k < H_) && yr[4 + r + k] != yv);
            if (!done && hit) { g2 = (float)(k * k); done = true; }
        }
        if (__any(!done)) {              // rare: unresolved past k=4
            for (int k = 5; k < H_; ++k) {
                const int hu = h - k, hd = h + k;
                const int u = yb[max(hu, 0) * W_ + tx];
                const int dn = yb[min(hd, H_ - 1) * W_ + tx];
                const bool hit = ((hu >= 0) && u != yv) || ((hd < H_) && dn != yv);
                if (!done && hit) { g2 = (float)(k * k); done = true; }
                if (__all(done)) break;
                if (hu < 0 && hd >= H_) break;
            }
        }
        g2v[r] = g2;
    }

    __shared__ uint2 s2[RPB][W_];        // {g2 bits, label} per row
#pragma unroll
    for (int r = 0; r < RPB; ++r)
        s2[r][tx] = make_uint2(__float_as_uint(g2v[r]), (unsigned)yr[4 + r]);
    __syncthreads();

    // ---- exact min-plus along W per row, adaptive radius, clamped indices ----
    // cand(j,k) = (label[j]==yv ? g2col[j] : 0) + k^2 ; a clamped j is
    // dominated by its true-k evaluation, so clamping never changes the min.
#define CAND(SR, CU, J, K2) ({ int j_ = (J); j_ = min(max(j_, 0), W_ - 1);     \
                               const uint2 v_ = (SR)[j_];                      \
                               (((v_.y == (CU)) ? __uint_as_float(v_.x) : 0.0f) + (K2)); })
    float mv[RPB];
#pragma unroll
    for (int r = 0; r < RPB; ++r) {
        const unsigned cu = (unsigned)yr[4 + r];
        const uint2* sr = s2[r];
        float m = g2v[r];                // j = x candidate
        m = fminf(m, fminf(CAND(sr, cu, tx - 1, 1.0f),  CAND(sr, cu, tx + 1, 1.0f)));
        m = fminf(m, fminf(CAND(sr, cu, tx - 2, 4.0f),  CAND(sr, cu, tx + 2, 4.0f)));
        m = fminf(m, fminf(CAND(sr, cu, tx - 3, 9.0f),  CAND(sr, cu, tx + 3, 9.0f)));
        m = fminf(m, fminf(CAND(sr, cu, tx - 4, 16.0f), CAND(sr, cu, tx + 4, 16.0f)));
        mv[r] = m;
    }
#pragma unroll
    for (int r = 0; r < RPB; ++r) {
        if (__any(mv[r] > 25.0f)) {      // some lane could still improve at k>=5
            const unsigned cu = (unsigned)yr[4 + r];
            const uint2* sr = s2[r];
            float m = mv[r];
            float k2 = 25.0f, tk1 = 11.0f;   // k^2, 2k+1 (exact ints in f32)
            for (int k = 5; k < W_; ++k) {
                m = fminf(m, fminf(CAND(sr, cu, tx - k, k2), CAND(sr, cu, tx + k, k2)));
                k2 += tk1; tk1 += 2.0f;
                if (__all(k2 >= m)) break;   // next k can't improve any lane
            }
            mv[r] = m;
        }
    }
#undef CAND

    // ---- softmax + contribution split, accumulated across the 4 rows ----
    float A[C_] = {0.f, 0.f, 0.f, 0.f};
    float M[C_] = {0.f, 0.f, 0.f, 0.f};
    float T = 0.0f;
#pragma unroll
    for (int r = 0; r < RPB; ++r) {
        const int yv = yr[4 + r];
        const float d = sqrtf(mv[r]);    // own-class distance (>= 1)
        const float x0 = xv[r][0], x1 = xv[r][1], x2 = xv[r][2], x3 = xv[r][3];
        const float xm = fmaxf(fmaxf(x0, x1), fmaxf(x2, x3));
        const float e0 = __expf(x0 - xm), e1 = __expf(x1 - xm);
        const float e2 = __expf(x2 - xm), e3 = __expf(x3 - xm);
        const float se = e0 + e1 + e2 + e3;
        const float inv = 1.0f / se;
        const float ec = (yv == 0) ? e0 : (yv == 1) ? e1 : (yv == 2) ? e2 : e3;
        const float p = ec * inv;        // own-class probability
        T += (se - ec) * inv;            // other 3 classes: r = 1
        const float a = p * d;           // own class: needs /(mx+eps) later
#pragma unroll
        for (int c = 0; c < C_; ++c) {
            A[c] += (yv == c) ? a : 0.0f;
            M[c] = fmaxf(M[c], (yv == c) ? d : 0.0f);
        }
    }

    // ---- fixed-order wave butterfly + cross-wave combine (9 quantities) ----
#pragma unroll
    for (int off = 1; off < 64; off <<= 1) {
#pragma unroll
        for (int c = 0; c < C_; ++c) {
            A[c] += __shfl_xor(A[c], off);
            M[c] = fmaxf(M[c], __shfl_xor(M[c], off));
        }
        T += __shfl_xor(T, off);
    }
    __shared__ float red[4][9];
    const int wid = tx >> 6;
    if ((tx & 63) == 0) {
#pragma unroll
        for (int c = 0; c < C_; ++c) { red[wid][c] = A[c]; red[wid][4 + c] = M[c]; }
        red[wid][8] = T;
    }
    __syncthreads();
    if (tx < 9) {   // slots 0-3: A sums, 4-7: M maxes, 8: T sum
        const float v0 = red[0][tx], v1 = red[1][tx], v2 = red[2][tx], v3 = red[3][tx];
        const float r = (tx >= 4 && tx < 8) ? fmaxf(fmaxf(v0, v1), fmaxf(v2, v3))
                                            : (v0 + v1) + (v2 + v3);
        P[tx * NBLK + blk] = r;
    }
}

// Single block: P[slot][b*64+rb] -> out = (T - sum_{b,c} A/(M+1e-15)) / (B*C*H*W)
__global__ void finish_kernel(const float* __restrict__ P, float* __restrict__ out) {
    const int t = threadIdx.x;           // 256 threads; 32 groups of 8 = (b,c)
    const int g = t >> 3, l = t & 7;
    const int b = g >> 2, c = g & 3;
    const float* Pa = P + c * NBLK + b * 64;
    const float* Pm = P + (4 + c) * NBLK + b * 64;
    float a = 0.0f, mm = 0.0f;
#pragma unroll
    for (int i = 0; i < 8; ++i) {        // 64 partials per (b,c)
        a += Pa[l + (i << 3)];
        mm = fmaxf(mm, Pm[l + (i << 3)]);
    }
#pragma unroll
    for (int off = 1; off < 8; off <<= 1) {
        a += __shfl_xor(a, off);
        mm = fmaxf(mm, __shfl_xor(mm, off));
    }
    const float* Pt = P + 8 * NBLK;
    float tt = Pt[t] + Pt[t + 256];
#pragma unroll
    for (int off = 1; off < 64; off <<= 1) tt += __shfl_xor(tt, off);
    __shared__ float sV[32];
    __shared__ float sT[4];
    if (l == 0) sV[g] = a / (mm + 1e-15f);
    if ((t & 63) == 0) sT[t >> 6] = tt;
    __syncthreads();
    if (t == 0) {
        float S = 0.0f;
#pragma unroll
        for (int i = 0; i < 32; ++i) S += sV[i];
        const float T = (sT[0] + sT[1]) + (sT[2] + sT[3]);
        out[0] = (T - S) * (1.0f / 2097152.0f);   // / (B*C*H*W)
    }
}

extern "C" void kernel_launch(void* const* d_in, const int* in_sizes, int n_in,
                              void* d_out, int out_size, void* d_ws, size_t ws_size,
                              hipStream_t stream) {
    const float* x = (const float*)d_in[0];   // [B, C, H, W] f32
    const int* y = (const int*)d_in[1];       // [B, 1, H, W] i32
    float* out = (float*)d_out;               // scalar f32
    float* P = (float*)d_ws;                  // [9][NBLK] partials (18 KB)

    fused_kernel<<<NBLK, 256, 0, stream>>>(y, x, P);
    finish_kernel<<<1, 256, 0, stream>>>(P, out);
}